// Round 14
// baseline (123.660 us; speedup 1.0000x reference)
//
#include <hip/hip_runtime.h>
#include <hip/hip_bf16.h>

// Gemma4AudioRelativePosition — fused bf16-MFMA, round 14.
// out[b,h,n,s,c] = sum_d q[s,d]*k[c,d] + (0<=c-s<=127 ? BD[s,c-s] : 0)
// R14 = R13 (nt stores + no-drain barriers, 118us) made PERSISTENT over 2
// work units per block: grid 1024 = exactly 4 blocks/CU all resident (no
// second dispatch set), and unit-1's K chunk-0 is prefetched during unit-0's
// last chunk so the K stream never goes cold at the unit boundary. BD LDS
// rows are wave-private -> unit-1's BD phase needs no extra barrier.

typedef __bf16 bf16x8 __attribute__((ext_vector_type(8)));
typedef unsigned short u16x8 __attribute__((ext_vector_type(8)));
typedef unsigned int u32x4 __attribute__((ext_vector_type(4)));
typedef float f32x4 __attribute__((ext_vector_type(4)));

__device__ __forceinline__ unsigned short f2bf(float f) {
    unsigned u = __float_as_uint(f);
    u = (u + 0x7FFFu + ((u >> 16) & 1u)) >> 16;   // RNE
    return (unsigned short)u;
}
__device__ __forceinline__ float bf2f(unsigned short s) {
    return __uint_as_float(((unsigned)s) << 16);
}
// truncation pack: two fp32 -> packed 2x bf16
__device__ __forceinline__ unsigned pk2(float a, float b) {
    return (__float_as_uint(a) >> 16) | (__float_as_uint(b) & 0xFFFF0000u);
}

// Raw barrier: order LDS ops (lgkmcnt) but leave global loads AND nt stores
// in flight across the barrier.
__device__ __forceinline__ void barrier_no_vm_drain() {
    asm volatile("s_waitcnt lgkmcnt(0)" ::: "memory");
    __builtin_amdgcn_s_barrier();
}

// ---------------- kernel 1: proj = sin_emb @ W_pos^T  (bf16 out) ----------------
// grid 1024 = (p 0..127) x (jq 0..7); block computes proj[p, jq*64 .. jq*64+64)
__global__ __launch_bounds__(256) void proj_kernel(const float* __restrict__ W,
                                                   unsigned short* __restrict__ projw) {
    __shared__ float se[512];
    int bid = blockIdx.x;
    int p  = bid >> 3;      // 0..127
    int jq = bid & 7;       // 0..7
    int t = threadIdx.x;    // 0..255
    const float LOGINC = (float)(9.210340371976184 / 255.0);  // ln(1e4)/255
    float pos = (float)(127 - p);
    float inv = expf(-LOGINC * (float)t);
    float ang = pos * inv;
    se[t]       = sinf(ang);
    se[t + 256] = cosf(ang);
    __syncthreads();
    int j  = jq * 64 + (t >> 2);
    int tq = t & 3;
    const float4* wr = (const float4*)(W + (size_t)j * 512 + tq * 128);
    const float4* sr = (const float4*)(se + tq * 128);
    float a = 0.f;
#pragma unroll
    for (int i = 0; i < 32; ++i) {
        float4 wv = wr[i];
        float4 sv = sr[i];
        a += sv.x * wv.x + sv.y * wv.y + sv.z * wv.z + sv.w * wv.w;
    }
    a += __shfl_xor(a, 1);
    a += __shfl_xor(a, 2);
    if (tq == 0) projw[p * 512 + j] = f2bf(a);
}

// ---------------- kernel 2: fused AC + skewed BD (persistent, 2 units) --------
__global__ __launch_bounds__(256, 4) void fused_kernel(const float* __restrict__ Q,
                                                       const float* __restrict__ Kg,
                                                       const unsigned short* __restrict__ projw,
                                                       float* __restrict__ out) {
    __shared__ unsigned short BDs[128 * 128];   // BD[s][(s+p)&127], bf16, swizzled (32KB)
    __shared__ unsigned short Klds[64 * 64];    // one 64-row K chunk, bf16, swizzled (8KB)

    // XCD-aware remap over 1024 blocks; each block owns units 2*wpair, 2*wpair+1
    // (h = 2j, 2j+1 of the same (b,n)).
    int bid = blockIdx.x;
    int wpair = (bid & 7) * 128 + (bid >> 3);   // 0..1023
    int wid0 = wpair * 2;
    int h0 = wid0 & 7;
    int n  = (wid0 >> 3) & 63;
    int b  = wid0 >> 9;

    const float* qbase0 = Q  + ((size_t)(b * 64 + n) * 128) * 512 + h0 * 64;
    const float* kbase0 = Kg + ((size_t)(b * 64 + n) * 256) * 512 + h0 * 64;

    int tid = threadIdx.x;
    int w  = tid >> 6;     // wave 0..3 -> s-stripe [32w, 32w+32)
    int l  = tid & 63;
    int lo = l & 15;
    int hi = l >> 4;
    int rq = l >> 4;       // 0..3: row-in-quad for staging
    int cq = l & 15;       // 0..15: float4 col slot for staging (full-row pattern)

    // ---- unit-0 chunk-0 K prefetch FIRST (4 rows x 256B contiguous / instr)
    float4 kpre[4];
#pragma unroll
    for (int it = 0; it < 4; ++it) {
        int row = w * 16 + it * 4 + rq;     // chunk-local row 0..63
        kpre[it] = *(const float4*)(kbase0 + (size_t)row * 512 + cq * 4);
    }

    const unsigned short* pbase0 = projw + h0 * 64;

    for (int u = 0; u < 2; ++u) {
        const float* qbase = qbase0 + u * 64;           // h0+u -> +64 cols
        const float* kbase = kbase0 + u * 64;
        const unsigned short* pbase = pbase0 + u * 64;
        size_t obase = ((size_t)((b * 8 + h0 + u) * 64 + n)) * (128 * 256);

        // ---- A-fragments: global fp32 -> reg bf16
        bf16x8 afrag[2][2];
#pragma unroll
        for (int i2 = 0; i2 < 2; ++i2) {
            int row = w * 32 + i2 * 16 + lo;
            const float* ar = qbase + (size_t)row * 512;
#pragma unroll
            for (int kk = 0; kk < 2; ++kk) {
                float4 va = *(const float4*)(ar + kk * 32 + hi * 8);
                float4 vb = *(const float4*)(ar + kk * 32 + hi * 8 + 4);
                u16x8 uu;
                uu[0] = f2bf(va.x); uu[1] = f2bf(va.y); uu[2] = f2bf(va.z); uu[3] = f2bf(va.w);
                uu[4] = f2bf(vb.x); uu[5] = f2bf(vb.y); uu[6] = f2bf(vb.z); uu[7] = f2bf(vb.w);
                afrag[i2][kk] = __builtin_bit_cast(bf16x8, uu);
            }
        }

        // ---- BD phase: D col(lo)=s, row(hi,jr)=p; skew-store to BDs.
        // BDs rows [32w,32w+32) are written AND read only by wave w -> no
        // barrier needed, even at the u0->u1 transition.
#pragma unroll 2
        for (int pj = 0; pj < 8; ++pj) {
            int prow = pj * 16 + lo;
            const unsigned short* pr = pbase + (size_t)prow * 512;
            bf16x8 pf0 = *(const bf16x8*)(pr + hi * 8);
            bf16x8 pf1 = *(const bf16x8*)(pr + 32 + hi * 8);
#pragma unroll
            for (int i2 = 0; i2 < 2; ++i2) {
                f32x4 acc = {0.f, 0.f, 0.f, 0.f};
                acc = __builtin_amdgcn_mfma_f32_16x16x32_bf16(pf0, afrag[i2][0], acc, 0, 0, 0);
                acc = __builtin_amdgcn_mfma_f32_16x16x32_bf16(pf1, afrag[i2][1], acc, 0, 0, 0);
                int s  = w * 32 + i2 * 16 + lo;
                int pb = pj * 16 + hi * 4;
#pragma unroll
                for (int jr = 0; jr < 4; ++jr) {
                    int cw = (s + pb + jr) & 127;   // band 128 wide -> mod-128 bijection
                    BDs[s * 128 + (cw ^ ((s & 7) << 3))] = f2bf(acc[jr]);
                }
            }
        }

        // ---- Main loop: 4 K-chunks of 64 rows, no-drain barriers.
        for (int ch = 0; ch < 4; ++ch) {
            if (ch > 0 || u > 0) barrier_no_vm_drain();  // Klds overwrite guard

            // pack prefetched chunk into LDS (swizzled)
#pragma unroll
            for (int it = 0; it < 4; ++it) {
                int row = w * 16 + it * 4 + rq;
                float4 v = kpre[it];
                uint2 pk;
                pk.x = pk2(v.x, v.y);
                pk.y = pk2(v.z, v.w);
                int col = cq * 4;
                *reinterpret_cast<uint2*>(&Klds[row * 64 + (col ^ ((row & 7) << 3))]) = pk;
            }

            // refill: next chunk of this unit, or unit-1 chunk-0 at u0/ch3
            if (ch < 3) {
#pragma unroll
                for (int it = 0; it < 4; ++it) {
                    int row = w * 16 + it * 4 + rq;
                    kpre[it] = *(const float4*)(kbase + (size_t)((ch + 1) * 64 + row) * 512 + cq * 4);
                }
            } else if (u == 0) {
#pragma unroll
                for (int it = 0; it < 4; ++it) {
                    int row = w * 16 + it * 4 + rq;
                    kpre[it] = *(const float4*)(kbase0 + 64 + (size_t)row * 512 + cq * 4);
                }
            }

            barrier_no_vm_drain();   // staging visible; loads+nt stores in flight

            // compute cj tiles of this chunk
#pragma unroll
            for (int cjl = 0; cjl < 4; ++cjl) {
                int cj = ch * 4 + cjl;
                int krl = cjl * 16 + lo;
                bf16x8 kf0 = *(const bf16x8*)&Klds[krl * 64 + ((hi * 8)      ^ ((krl & 7) << 3))];
                bf16x8 kf1 = *(const bf16x8*)&Klds[krl * 64 + ((32 + hi * 8) ^ ((krl & 7) << 3))];
#pragma unroll
                for (int i2 = 0; i2 < 2; ++i2) {
                    int stile = 2 * w + i2;
                    f32x4 acc = {0.f, 0.f, 0.f, 0.f};
                    acc = __builtin_amdgcn_mfma_f32_16x16x32_bf16(kf0, afrag[i2][0], acc, 0, 0, 0);
                    acc = __builtin_amdgcn_mfma_f32_16x16x32_bf16(kf1, afrag[i2][1], acc, 0, 0, 0);
                    int s  = stile * 16 + lo;
                    int cb = cj * 16 + hi * 4;
                    if (cj >= stile && cj <= stile + 8) {   // band-active (uniform/wave)
                        uint2 pk = *(const uint2*)&BDs[s * 128 + ((cb & 127) ^ ((s & 7) << 3))];
                        unsigned short v0 = (unsigned short)(pk.x & 0xffffu);
                        unsigned short v1 = (unsigned short)(pk.x >> 16);
                        unsigned short v2 = (unsigned short)(pk.y & 0xffffu);
                        unsigned short v3 = (unsigned short)(pk.y >> 16);
                        if ((unsigned)(cb + 0 - s) < 128u) acc[0] += bf2f(v0);
                        if ((unsigned)(cb + 1 - s) < 128u) acc[1] += bf2f(v1);
                        if ((unsigned)(cb + 2 - s) < 128u) acc[2] += bf2f(v2);
                        if ((unsigned)(cb + 3 - s) < 128u) acc[3] += bf2f(v3);
                    }
                    // Nontemporal: stream the output past L2/L3 (write-once data).
                    __builtin_nontemporal_store(
                        *reinterpret_cast<f32x4*>(&acc),
                        reinterpret_cast<f32x4*>(&out[obase + (size_t)s * 256 + cb]));
                }
            }
        }
    }
}

extern "C" void kernel_launch(void* const* d_in, const int* in_sizes, int n_in,
                              void* d_out, int out_size, void* d_ws, size_t ws_size,
                              hipStream_t stream) {
    const float* Q  = (const float*)d_in[0];
    const float* Kg = (const float*)d_in[1];
    const float* W  = (const float*)d_in[2];
    float* out = (float*)d_out;
    unsigned short* projw = (unsigned short*)d_ws;   // 128*512 bf16 = 128 KB

    hipLaunchKernelGGL(proj_kernel, dim3(1024), dim3(256), 0, stream, W, projw);
    hipLaunchKernelGGL(fused_kernel, dim3(1024), dim3(256), 0, stream, Q, Kg, projw, out);
}

// Round 15
// 118.031 us; speedup vs baseline: 1.0477x; 1.0477x over previous
//
#include <hip/hip_runtime.h>
#include <hip/hip_bf16.h>

// Gemma4AudioRelativePosition — fused bf16-MFMA, round 15 = REVERT to R10,
// the measured best (117.8us): R5 structure (staged K, 4-row x 256B staging
// loads, 4x64-row chunks, T14 prefetch, XCD remap) + nontemporal stores.
// All other tested levers (occupancy up/down, barrier semantics, prefetch
// depth, store pairing/shape, persistence) measured neutral or worse.

typedef __bf16 bf16x8 __attribute__((ext_vector_type(8)));
typedef unsigned short u16x8 __attribute__((ext_vector_type(8)));
typedef unsigned int u32x4 __attribute__((ext_vector_type(4)));
typedef float f32x4 __attribute__((ext_vector_type(4)));

__device__ __forceinline__ unsigned short f2bf(float f) {
    unsigned u = __float_as_uint(f);
    u = (u + 0x7FFFu + ((u >> 16) & 1u)) >> 16;   // RNE
    return (unsigned short)u;
}
__device__ __forceinline__ float bf2f(unsigned short s) {
    return __uint_as_float(((unsigned)s) << 16);
}
// truncation pack: two fp32 -> packed 2x bf16
__device__ __forceinline__ unsigned pk2(float a, float b) {
    return (__float_as_uint(a) >> 16) | (__float_as_uint(b) & 0xFFFF0000u);
}

// ---------------- kernel 1: proj = sin_emb @ W_pos^T  (bf16 out) ----------------
// grid 1024 = (p 0..127) x (jq 0..7); block computes proj[p, jq*64 .. jq*64+64)
__global__ __launch_bounds__(256) void proj_kernel(const float* __restrict__ W,
                                                   unsigned short* __restrict__ projw) {
    __shared__ float se[512];
    int bid = blockIdx.x;
    int p  = bid >> 3;      // 0..127
    int jq = bid & 7;       // 0..7
    int t = threadIdx.x;    // 0..255
    const float LOGINC = (float)(9.210340371976184 / 255.0);  // ln(1e4)/255
    float pos = (float)(127 - p);
    float inv = expf(-LOGINC * (float)t);
    float ang = pos * inv;
    se[t]       = sinf(ang);
    se[t + 256] = cosf(ang);
    __syncthreads();
    int j  = jq * 64 + (t >> 2);
    int tq = t & 3;
    const float4* wr = (const float4*)(W + (size_t)j * 512 + tq * 128);
    const float4* sr = (const float4*)(se + tq * 128);
    float a = 0.f;
#pragma unroll
    for (int i = 0; i < 32; ++i) {
        float4 wv = wr[i];
        float4 sv = sr[i];
        a += sv.x * wv.x + sv.y * wv.y + sv.z * wv.z + sv.w * wv.w;
    }
    a += __shfl_xor(a, 1);
    a += __shfl_xor(a, 2);
    if (tq == 0) projw[p * 512 + j] = f2bf(a);
}

// ---------------- kernel 2: fused AC + skewed BD ----------------
__global__ __launch_bounds__(256, 4) void fused_kernel(const float* __restrict__ Q,
                                                       const float* __restrict__ Kg,
                                                       const unsigned short* __restrict__ projw,
                                                       float* __restrict__ out) {
    __shared__ unsigned short BDs[128 * 128];   // BD[s][(s+p)&127], bf16, swizzled (32KB)
    __shared__ unsigned short Klds[64 * 64];    // one 64-row K chunk, bf16, swizzled (8KB)

    // XCD-aware remap: h fastest within an XCD's range.
    int bid = blockIdx.x;
    int wid = (bid & 7) * 256 + (bid >> 3);   // 2048 blocks = 8 XCD x 256
    int h = wid & 7;
    int n = (wid >> 3) & 63;
    int b = wid >> 9;

    const float* qbase = Q  + ((size_t)(b * 64 + n) * 128) * 512 + h * 64;
    const float* kbase = Kg + ((size_t)(b * 64 + n) * 256) * 512 + h * 64;

    int tid = threadIdx.x;
    int w  = tid >> 6;     // wave 0..3 -> s-stripe [32w, 32w+32)
    int l  = tid & 63;
    int lo = l & 15;
    int hi = l >> 4;
    int rq = l >> 4;       // 0..3: row-in-quad for staging
    int cq = l & 15;       // 0..15: float4 col slot for staging (full-row pattern)

    // ---- T14: issue K chunk-0 prefetch FIRST (4 rows x 256B contiguous / instr)
    float4 kpre[4];
#pragma unroll
    for (int it = 0; it < 4; ++it) {
        int row = w * 16 + it * 4 + rq;     // chunk-local row 0..63
        kpre[it] = *(const float4*)(kbase + (size_t)row * 512 + cq * 4);
    }

    // ---- A-fragments: global fp32 -> reg bf16 (each q element read exactly once)
    bf16x8 afrag[2][2];
#pragma unroll
    for (int i2 = 0; i2 < 2; ++i2) {
        int row = w * 32 + i2 * 16 + lo;
        const float* ar = qbase + (size_t)row * 512;
#pragma unroll
        for (int kk = 0; kk < 2; ++kk) {
            float4 va = *(const float4*)(ar + kk * 32 + hi * 8);
            float4 vb = *(const float4*)(ar + kk * 32 + hi * 8 + 4);
            u16x8 u;
            u[0] = f2bf(va.x); u[1] = f2bf(va.y); u[2] = f2bf(va.z); u[3] = f2bf(va.w);
            u[4] = f2bf(vb.x); u[5] = f2bf(vb.y); u[6] = f2bf(vb.z); u[7] = f2bf(vb.w);
            afrag[i2][kk] = __builtin_bit_cast(bf16x8, u);
        }
    }

    // ---- Phase 1: BD = proj @ A^T (swapped operands) -> D: col(lo)=s, row(hi,jr)=p
    // Skew-store bf16 to BDs. Same wave writes & reads its own s rows -> no barrier.
    const unsigned short* pbase = projw + h * 64;
#pragma unroll 2
    for (int pj = 0; pj < 8; ++pj) {
        int prow = pj * 16 + lo;
        const unsigned short* pr = pbase + (size_t)prow * 512;
        bf16x8 pf0 = *(const bf16x8*)(pr + hi * 8);
        bf16x8 pf1 = *(const bf16x8*)(pr + 32 + hi * 8);
#pragma unroll
        for (int i2 = 0; i2 < 2; ++i2) {
            f32x4 acc = {0.f, 0.f, 0.f, 0.f};
            acc = __builtin_amdgcn_mfma_f32_16x16x32_bf16(pf0, afrag[i2][0], acc, 0, 0, 0);
            acc = __builtin_amdgcn_mfma_f32_16x16x32_bf16(pf1, afrag[i2][1], acc, 0, 0, 0);
            int s  = w * 32 + i2 * 16 + lo;
            int pb = pj * 16 + hi * 4;
#pragma unroll
            for (int jr = 0; jr < 4; ++jr) {
                int cw = (s + pb + jr) & 127;     // band 128 wide -> mod-128 bijection
                BDs[s * 128 + (cw ^ ((s & 7) << 3))] = f2bf(acc[jr]);
            }
        }
    }

    // ---- Main loop: 4 K-chunks of 64 rows. Stage (regs->LDS), prefetch next,
    // barrier, compute 4 cj tiles, barrier.
    size_t obase = ((size_t)((b * 8 + h) * 64 + n)) * (128 * 256);

    for (int ch = 0; ch < 4; ++ch) {
        if (ch) __syncthreads();   // prev chunk's reads done before overwrite

        // pack prefetched chunk into LDS (swizzled)
#pragma unroll
        for (int it = 0; it < 4; ++it) {
            int row = w * 16 + it * 4 + rq;     // chunk-local row
            float4 v = kpre[it];
            uint2 pk;
            pk.x = pk2(v.x, v.y);
            pk.y = pk2(v.z, v.w);
            int col = cq * 4;
            *reinterpret_cast<uint2*>(&Klds[row * 64 + (col ^ ((row & 7) << 3))]) = pk;
        }

        // issue next chunk's prefetch (T14: in flight across compute below)
        if (ch < 3) {
#pragma unroll
            for (int it = 0; it < 4; ++it) {
                int row = w * 16 + it * 4 + rq;
                kpre[it] = *(const float4*)(kbase + (size_t)((ch + 1) * 64 + row) * 512 + cq * 4);
            }
        }

        __syncthreads();           // staging visible to all waves

        // compute cj tiles of this chunk
#pragma unroll
        for (int cjl = 0; cjl < 4; ++cjl) {
            int cj = ch * 4 + cjl;
            int krl = cjl * 16 + lo;    // chunk-local K row
            bf16x8 kf0 = *(const bf16x8*)&Klds[krl * 64 + ((hi * 8)      ^ ((krl & 7) << 3))];
            bf16x8 kf1 = *(const bf16x8*)&Klds[krl * 64 + ((32 + hi * 8) ^ ((krl & 7) << 3))];
#pragma unroll
            for (int i2 = 0; i2 < 2; ++i2) {
                int stile = 2 * w + i2;
                f32x4 acc = {0.f, 0.f, 0.f, 0.f};
                acc = __builtin_amdgcn_mfma_f32_16x16x32_bf16(kf0, afrag[i2][0], acc, 0, 0, 0);
                acc = __builtin_amdgcn_mfma_f32_16x16x32_bf16(kf1, afrag[i2][1], acc, 0, 0, 0);
                int s  = stile * 16 + lo;
                int cb = cj * 16 + hi * 4;
                if (cj >= stile && cj <= stile + 8) {   // band-active (uniform/wave)
                    uint2 pk = *(const uint2*)&BDs[s * 128 + ((cb & 127) ^ ((s & 7) << 3))];
                    unsigned short v0 = (unsigned short)(pk.x & 0xffffu);
                    unsigned short v1 = (unsigned short)(pk.x >> 16);
                    unsigned short v2 = (unsigned short)(pk.y & 0xffffu);
                    unsigned short v3 = (unsigned short)(pk.y >> 16);
                    if ((unsigned)(cb + 0 - s) < 128u) acc[0] += bf2f(v0);
                    if ((unsigned)(cb + 1 - s) < 128u) acc[1] += bf2f(v1);
                    if ((unsigned)(cb + 2 - s) < 128u) acc[2] += bf2f(v2);
                    if ((unsigned)(cb + 3 - s) < 128u) acc[3] += bf2f(v3);
                }
                // Nontemporal: stream the output past L2/L3 (write-once data).
                __builtin_nontemporal_store(
                    *reinterpret_cast<f32x4*>(&acc),
                    reinterpret_cast<f32x4*>(&out[obase + (size_t)s * 256 + cb]));
            }
        }
    }
}

extern "C" void kernel_launch(void* const* d_in, const int* in_sizes, int n_in,
                              void* d_out, int out_size, void* d_ws, size_t ws_size,
                              hipStream_t stream) {
    const float* Q  = (const float*)d_in[0];
    const float* Kg = (const float*)d_in[1];
    const float* W  = (const float*)d_in[2];
    float* out = (float*)d_out;
    unsigned short* projw = (unsigned short*)d_ws;   // 128*512 bf16 = 128 KB

    hipLaunchKernelGGL(proj_kernel, dim3(1024), dim3(256), 0, stream, W, projw);
    hipLaunchKernelGGL(fused_kernel, dim3(2048), dim3(256), 0, stream, Q, Kg, projw, out);
}